// Round 4
// baseline (2879.638 us; speedup 1.0000x reference)
//
#include <hip/hip_runtime.h>
#include <hip/hip_bf16.h>
#include <cstdint>

#define HWP    4096
#define CDIM   256
#define KCODES 8192
#define NROWS  32768
#define NKB    64          // 8192 / 128 code-blocks
#define LDA    72          // fp16 elems per LDS row: 64 + 8 pad (16 B) -> 2-way conflicts only

typedef _Float16 f16x8 __attribute__((ext_vector_type(8)));
typedef float    f32x4 __attribute__((ext_vector_type(4)));

// ---- index-aware top-2 insert (first-index on value ties, dedup by index) ----
__device__ __forceinline__ void ins2(float v, int i,
                                     float& v1, int& i1, float& v2, int& i2) {
    if (i == i1 || i == i2) return;
    bool b1 = (v > v1) || (v == v1 && i < i1);
    bool b2 = (v > v2) || (v == v2 && i < i2);
    if (b1) { v2 = v1; i2 = i1; v1 = v; i1 = i; }
    else if (b2) { v2 = v; i2 = i; }
}

// =============== Kernel 1a: transpose+convert x -> xT [N][C] fp16 =============
__global__ __launch_bounds__(256) void split_x_kernel(const float* __restrict__ x,
                                                      _Float16* __restrict__ xh) {
    __shared__ float tile[64][65];
    int pb = blockIdx.x, cbk = blockIdx.y, b = blockIdx.z;
    int t = threadIdx.x;
    int p0 = pb * 64, c0 = cbk * 64;
    int pl = t & 63, cl = t >> 6;
    const float* src = x + ((size_t)b * CDIM + c0) * HWP + p0;
    #pragma unroll 4
    for (int i = 0; i < 16; ++i) {
        int c = cl * 16 + i;
        tile[c][pl] = src[(size_t)c * HWP + pl];
    }
    __syncthreads();
    int p = t >> 2, cq = (t & 3) * 16;
    size_t n = (size_t)b * HWP + p0 + p;
    alignas(16) _Float16 hbuf[16];
    #pragma unroll
    for (int j = 0; j < 16; ++j)
        hbuf[j] = (_Float16)tile[cq + j][p];
    *(int4*)(xh + n * CDIM + c0 + cq)     = ((int4*)hbuf)[0];
    *(int4*)(xh + n * CDIM + c0 + cq + 8) = ((int4*)hbuf)[1];
}

// =============== Kernel 1b: convert codebook [K][C] -> fp16 ===================
__global__ __launch_bounds__(256) void split_cb_kernel(const float* __restrict__ cb,
                                                       _Float16* __restrict__ ch) {
    int i4 = blockIdx.x * 256 + threadIdx.x;          // 2048 blocks
    float4 v = ((const float4*)cb)[i4];
    alignas(8) _Float16 h[4];
    h[0] = (_Float16)v.x; h[1] = (_Float16)v.y;
    h[2] = (_Float16)v.z; h[3] = (_Float16)v.w;
    *(uint2*)(ch + (size_t)i4 * 4) = *(uint2*)h;
}

// =============== Kernel 2: fp16 MFMA GEMM + per-(row,kb) top-2 ================
// 1D grid 16384, 256 threads (4 waves, 2x2 wave grid: 64 rows x 64 codes each).
// Staging: global_load_dwordx4 -> VGPR -> ds_write_b128 (NO global_load_lds).
__global__ __launch_bounds__(256, 4) void gemm_kernel(const _Float16* __restrict__ xh,
                                                      const _Float16* __restrict__ ch,
                                                      float4* __restrict__ ptop) {
    __shared__ _Float16 sA[128 * LDA];    // 18 KB
    __shared__ _Float16 sB[128 * LDA];    // 18 KB
    __shared__ float4   s_top[128 * 2];   // 4 KB epilogue scratch

    int t = threadIdx.x;
    // XCD-aware decode: per XCD a band of 32 mb values, kb fastest ->
    // fp16 codebook (4 MB) stays L2-resident per XCD, A tile reused 64x.
    int bid  = blockIdx.x;
    int xcd  = bid & 7;
    int loc  = bid >> 3;             // 0..2047
    int kb   = loc & 63;
    int mb   = xcd * 32 + (loc >> 6);
    int n0 = mb * 128, k0 = kb * 128;
    int w = t >> 6, lane = t & 63;
    int qq = lane >> 4, cc2 = lane & 15;
    int wm = w & 1, wn = w >> 1;

    // Staging geometry: 128 rows x 8 chunks(16B) per tile; 1024 chunks / 256 thr = 4 each.
    int sr = t >> 3;          // base row for chunk it: sr + it*32
    int sc = t & 7;           // 16B chunk within row

    f32x4 acc[4][4];
    f32x4 zero = {0.f, 0.f, 0.f, 0.f};
    #pragma unroll
    for (int mi = 0; mi < 4; ++mi)
        #pragma unroll
        for (int ni = 0; ni < 4; ++ni) acc[mi][ni] = zero;

    for (int cs = 0; cs < CDIM; cs += 64) {
        int4 a_reg[4], b_reg[4];
        #pragma unroll
        for (int it = 0; it < 4; ++it) {
            int r = sr + it * 32;
            a_reg[it] = *(const int4*)(xh + (size_t)(n0 + r) * CDIM + cs + sc * 8);
            b_reg[it] = *(const int4*)(ch + (size_t)(k0 + r) * CDIM + cs + sc * 8);
        }
        __syncthreads();
        #pragma unroll
        for (int it = 0; it < 4; ++it) {
            int r = sr + it * 32;
            *(int4*)(sA + r * LDA + sc * 8) = a_reg[it];
            *(int4*)(sB + r * LDA + sc * 8) = b_reg[it];
        }
        __syncthreads();

        #pragma unroll
        for (int kk = 0; kk < 2; ++kk) {
            f16x8 af[4], bf[4];
            #pragma unroll
            for (int mi = 0; mi < 4; ++mi) {
                int m = wm * 64 + mi * 16 + cc2;
                af[mi] = *(const f16x8*)(sA + m * LDA + kk * 32 + qq * 8);
            }
            #pragma unroll
            for (int ni = 0; ni < 4; ++ni) {
                int nn = wn * 64 + ni * 16 + cc2;
                bf[ni] = *(const f16x8*)(sB + nn * LDA + kk * 32 + qq * 8);
            }
            #pragma unroll
            for (int ni = 0; ni < 4; ++ni)
                #pragma unroll
                for (int mi = 0; mi < 4; ++mi)
                    acc[mi][ni] = __builtin_amdgcn_mfma_f32_16x16x32_f16(af[mi], bf[ni], acc[mi][ni], 0, 0, 0);
        }
    }

    // Epilogue: per-row top-2 over this wave's 64 codes, then merge halves.
    // C/D layout: col = lane&15, row = (lane>>4)*4 + reg.
    #pragma unroll
    for (int mi = 0; mi < 4; ++mi) {
        #pragma unroll
        for (int r = 0; r < 4; ++r) {
            float v1 = -3.4e38f, v2 = -3.4e38f;
            int   i1 = 0x7fffffff, i2 = 0x7fffffff;
            #pragma unroll
            for (int ni = 0; ni < 4; ++ni)
                ins2(acc[mi][ni][r], k0 + wn * 64 + ni * 16 + cc2, v1, i1, v2, i2);
            #pragma unroll
            for (int msk = 1; msk <= 8; msk <<= 1) {
                float ov1 = __shfl_xor(v1, msk); int oi1 = __shfl_xor(i1, msk);
                float ov2 = __shfl_xor(v2, msk); int oi2 = __shfl_xor(i2, msk);
                ins2(ov1, oi1, v1, i1, v2, i2);
                ins2(ov2, oi2, v1, i1, v2, i2);
            }
            if (cc2 == 0) {
                int row = wm * 64 + mi * 16 + qq * 4 + r;
                float4 e;
                e.x = v1; e.y = __int_as_float(i1);
                e.z = v2; e.w = __int_as_float(i2);
                s_top[row * 2 + wn] = e;
            }
        }
    }
    __syncthreads();
    if (t < 128) {
        float4 a = s_top[t * 2 + 0];
        float4 b = s_top[t * 2 + 1];
        float v1 = a.x; int i1 = __float_as_int(a.y);
        float v2 = a.z; int i2 = __float_as_int(a.w);
        ins2(b.x, __float_as_int(b.y), v1, i1, v2, i2);
        ins2(b.z, __float_as_int(b.w), v1, i1, v2, i2);
        float4 e;
        e.x = v1; e.y = __int_as_float(i1);
        e.z = v2; e.w = __int_as_float(i2);
        ptop[(size_t)kb * NROWS + n0 + t] = e;
    }
}

// =============== Kernel 3: merge 64 k-blocks -> global top-4 candidates =======
__global__ __launch_bounds__(256) void reduce_kernel(const float4* __restrict__ ptop,
                                                     int4* __restrict__ cand) {
    int n = blockIdx.x * 256 + threadIdx.x;   // 128 blocks
    float v[4] = {-3.4e38f, -3.4e38f, -3.4e38f, -3.4e38f};
    int   id[4] = {0x7fffffff, 0x7ffffffe, 0x7ffffffd, 0x7ffffffc};
    for (int kb = 0; kb < NKB; ++kb) {
        float4 e = ptop[(size_t)kb * NROWS + n];
        #pragma unroll
        for (int s = 0; s < 2; ++s) {
            float nv = s ? e.z : e.x;
            int   ni = __float_as_int(s ? e.w : e.y);
            bool dup = (ni == id[0]) | (ni == id[1]) | (ni == id[2]) | (ni == id[3]);
            if (!dup) {
                bool g0 = (nv > v[0]) || (nv == v[0] && ni < id[0]);
                bool g1 = (nv > v[1]) || (nv == v[1] && ni < id[1]);
                bool g2 = (nv > v[2]) || (nv == v[2] && ni < id[2]);
                bool g3 = (nv > v[3]) || (nv == v[3] && ni < id[3]);
                if (g0)      { v[3]=v[2]; id[3]=id[2]; v[2]=v[1]; id[2]=id[1]; v[1]=v[0]; id[1]=id[0]; v[0]=nv; id[0]=ni; }
                else if (g1) { v[3]=v[2]; id[3]=id[2]; v[2]=v[1]; id[2]=id[1]; v[1]=nv; id[1]=ni; }
                else if (g2) { v[3]=v[2]; id[3]=id[2]; v[2]=nv; id[2]=ni; }
                else if (g3) { v[3]=nv; id[3]=ni; }
            }
        }
    }
    cand[n] = make_int4(id[0], id[1], id[2], id[3]);
}

// =============== Kernel 4: exact fp32 rescore of 4 candidates + q write + loss =
__global__ __launch_bounds__(256) void rescore_kernel(const float* __restrict__ x,
                                                      const float* __restrict__ cb,
                                                      const int4* __restrict__ cand,
                                                      float* __restrict__ out,
                                                      float* __restrict__ loss_sum) {
    int blk = blockIdx.x;                 // 512 blocks, 64 rows each
    int b = blk >> 6;
    int p0 = (blk & 63) << 6;
    int t = threadIdx.x, w = t >> 6, lane = t & 63;
    size_t rowbase = (size_t)b * HWP + p0;
    int4 cd = cand[rowbase + lane];
    const float* xb = x + (size_t)b * CDIM * HWP + p0 + lane;
    const float* c0 = cb + (size_t)cd.x * CDIM;
    const float* c1 = cb + (size_t)cd.y * CDIM;
    const float* c2 = cb + (size_t)cd.z * CDIM;
    const float* c3 = cb + (size_t)cd.w * CDIM;
    float n2 = 0.f, d0 = 0.f, d1 = 0.f, d2 = 0.f, d3 = 0.f;
    for (int c = w * 64; c < w * 64 + 64; ++c) {
        float xv = xb[(size_t)c * HWP];
        n2 = fmaf(xv, xv, n2);
        d0 = fmaf(xv, c0[c], d0);
        d1 = fmaf(xv, c1[c], d1);
        d2 = fmaf(xv, c2[c], d2);
        d3 = fmaf(xv, c3[c], d3);
    }
    __shared__ float s_n2[4][64], s_d[4][4][64];
    __shared__ int   s_win[64];
    __shared__ float s_loss[64];
    s_n2[w][lane] = n2;
    s_d[0][w][lane] = d0; s_d[1][w][lane] = d1;
    s_d[2][w][lane] = d2; s_d[3][w][lane] = d3;
    __syncthreads();
    if (t < 64) {
        float N2 = s_n2[0][t] + s_n2[1][t] + s_n2[2][t] + s_n2[3][t];
        int4 cdt = cand[rowbase + t];
        int ids[4] = {cdt.x, cdt.y, cdt.z, cdt.w};
        float bD = -3.4e38f; int bI = 0x7fffffff;
        #pragma unroll
        for (int j = 0; j < 4; ++j) {
            float D = s_d[j][0][t] + s_d[j][1][t] + s_d[j][2][t] + s_d[j][3][t];
            if (D > bD || (D == bD && ids[j] < bI)) { bD = D; bI = ids[j]; }
        }
        s_win[t]  = bI;
        s_loss[t] = bD / fmaxf(sqrtf(N2), 1e-12f);
    }
    __syncthreads();
    if (w == 0) {
        float v = s_loss[lane];
        #pragma unroll
        for (int off = 32; off; off >>= 1) v += __shfl_down(v, off);
        if (lane == 0) atomicAdd(loss_sum, v);
    }
    int win = s_win[lane];
    const float* cw = cb + (size_t)win * CDIM;
    float* ob = out + (size_t)b * CDIM * HWP + p0 + lane;
    for (int c = w * 64; c < w * 64 + 64; ++c)
        ob[(size_t)c * HWP] = cw[c];
}

// =============== Kernel 5: finalize losses ====================================
__global__ void finalize_kernel(const float* __restrict__ loss_sum,
                                float* __restrict__ out) {
    if (threadIdx.x == 0) {
        float mean = loss_sum[0] / 32768.0f;
        out[8388608] = 0.25f * (1.0f - mean);
        out[8388609] = 1.0f  * (1.0f - mean);
    }
}

extern "C" void kernel_launch(void* const* d_in, const int* in_sizes, int n_in,
                              void* d_out, int out_size, void* d_ws, size_t ws_size,
                              hipStream_t stream) {
    const float* x  = (const float*)d_in[0];   // [8,256,64,64]
    const float* cb = (const float*)d_in[1];   // [8192,256]
    float* out = (float*)d_out;

    char* ws = (char*)d_ws;
    _Float16* xh   = (_Float16*)(ws);                     // 16,777,216 B
    _Float16* ch   = (_Float16*)(ws + 16777216);          //  4,194,304 B
    float4*   ptop = (float4*)  (ws + 20971520);          // 33,554,432 B
    int4*     cand = (int4*)    (ws + 54525952);          //    524,288 B
    float*    loss = (float*)   (ws + 55050240);          //          4 B

    hipMemsetAsync(loss, 0, 4, stream);
    split_x_kernel <<<dim3(64, 4, 8), 256, 0, stream>>>(x, xh);
    split_cb_kernel<<<2048,           256, 0, stream>>>(cb, ch);
    gemm_kernel    <<<16384,          256, 0, stream>>>(xh, ch, ptop);
    reduce_kernel  <<<128,            256, 0, stream>>>(ptop, cand);
    rescore_kernel <<<512,            256, 0, stream>>>(x, cb, cand, out, loss);
    finalize_kernel<<<1,              64,  0, stream>>>(loss, out);
}

// Round 5
// 913.397 us; speedup vs baseline: 3.1527x; 3.1527x over previous
//
#include <hip/hip_runtime.h>
#include <hip/hip_bf16.h>
#include <cstdint>

#define HWP    4096
#define CDIM   256
#define KCODES 8192
#define NROWS  32768
#define NKB    64          // 8192 / 128 code-blocks
#define LDA    72          // fp16 elems per LDS row: 64 + 8 pad -> conflict-light

typedef _Float16 f16x8 __attribute__((ext_vector_type(8)));
typedef float    f32x4 __attribute__((ext_vector_type(4)));
typedef unsigned long long u64;

// ---- sortable u64 key: (monotone f32) << 32 | (8191 - idx) -------------------
// max key == max value, ties -> smallest idx. Branch-free compare/merge.
__device__ __forceinline__ u64 key_make(float v, int idx) {
    uint32_t b = __float_as_uint(v);
    uint32_t m = (uint32_t)((int32_t)b >> 31) | 0x80000000u;
    uint32_t u = b ^ m;
    return ((u64)u << 32) | (uint32_t)(8191 - idx);
}
__device__ __forceinline__ int key_idx(u64 k) {
    return 8191 - (int)(k & 0xFFFFFFFFu);
}
// (k1,k2) = top-2 of {k1,k2,o1,o2}; inputs sorted pairs, distinct keys.
__device__ __forceinline__ void merge2(u64& k1, u64& k2, u64 o1, u64 o2) {
    u64 hi = k1 > o1 ? k1 : o1;
    u64 lo = k1 > o1 ? o1 : k1;
    u64 mx = k2 > o2 ? k2 : o2;
    k1 = hi;
    k2 = lo > mx ? lo : mx;
}
__device__ __forceinline__ void ins4(u64 c, u64 k[4]) {
    u64 a;
    a = k[0] > c ? k[0] : c;  c = k[0] > c ? c : k[0];  k[0] = a;
    a = k[1] > c ? k[1] : c;  c = k[1] > c ? c : k[1];  k[1] = a;
    a = k[2] > c ? k[2] : c;  c = k[2] > c ? c : k[2];  k[2] = a;
    k[3] = k[3] > c ? k[3] : c;
}

// =============== Kernel 1a: transpose+convert x -> xT [N][C] fp16 =============
__global__ __launch_bounds__(256) void split_x_kernel(const float* __restrict__ x,
                                                      _Float16* __restrict__ xh) {
    __shared__ float tile[64][65];
    int pb = blockIdx.x, cbk = blockIdx.y, b = blockIdx.z;
    int t = threadIdx.x;
    int p0 = pb * 64, c0 = cbk * 64;
    int pl = t & 63, cl = t >> 6;
    const float* src = x + ((size_t)b * CDIM + c0) * HWP + p0;
    #pragma unroll 4
    for (int i = 0; i < 16; ++i) {
        int c = cl * 16 + i;
        tile[c][pl] = src[(size_t)c * HWP + pl];
    }
    __syncthreads();
    int p = t >> 2, cq = (t & 3) * 16;
    size_t n = (size_t)b * HWP + p0 + p;
    alignas(16) _Float16 hbuf[16];
    #pragma unroll
    for (int j = 0; j < 16; ++j)
        hbuf[j] = (_Float16)tile[cq + j][p];
    *(int4*)(xh + n * CDIM + c0 + cq)     = ((int4*)hbuf)[0];
    *(int4*)(xh + n * CDIM + c0 + cq + 8) = ((int4*)hbuf)[1];
}

// =============== Kernel 1b: convert codebook [K][C] -> fp16 ===================
__global__ __launch_bounds__(256) void split_cb_kernel(const float* __restrict__ cb,
                                                       _Float16* __restrict__ ch) {
    int i4 = blockIdx.x * 256 + threadIdx.x;          // 2048 blocks
    float4 v = ((const float4*)cb)[i4];
    alignas(8) _Float16 h[4];
    h[0] = (_Float16)v.x; h[1] = (_Float16)v.y;
    h[2] = (_Float16)v.z; h[3] = (_Float16)v.w;
    *(uint2*)(ch + (size_t)i4 * 4) = *(uint2*)h;
}

// =============== Kernel 2: fp16 MFMA GEMM + branch-free per-(row,kb) top-2 ====
// 1D grid 16384, 256 threads = 4 waves; wave w owns rows w*32..+31 x all 128 codes.
__global__ __launch_bounds__(256) void gemm_kernel(const _Float16* __restrict__ xh,
                                                   const _Float16* __restrict__ ch,
                                                   ulonglong2* __restrict__ ptop) {
    __shared__ _Float16 sA[128 * LDA];    // 18 KB
    __shared__ _Float16 sB[128 * LDA];    // 18 KB

    int t = threadIdx.x;
    // XCD swizzle, mb fastest: B tile (64 KB) L2-hot across 32 consecutive
    // blocks; A band (2 MB/XCD) stays L2-resident across the kb sweep.
    int bid = blockIdx.x;
    int xcd = bid & 7;
    int loc = bid >> 3;              // 0..2047
    int mb  = xcd * 32 + (loc & 31);
    int kb  = loc >> 5;              // 0..63
    int n0 = mb * 128, k0 = kb * 128;
    int w = t >> 6, lane = t & 63;
    int qq = lane >> 4, cc2 = lane & 15;

    int sr = t >> 3;          // staging: row group, 32 rows per pass
    int sc = t & 7;           // 16B chunk within 128B row

    f32x4 acc[2][8];
    f32x4 zero = {0.f, 0.f, 0.f, 0.f};
    #pragma unroll
    for (int mi = 0; mi < 2; ++mi)
        #pragma unroll
        for (int ni = 0; ni < 8; ++ni) acc[mi][ni] = zero;

    for (int cs = 0; cs < CDIM; cs += 64) {
        int4 areg[4], breg[4];
        #pragma unroll
        for (int it = 0; it < 4; ++it) {
            int r = sr + it * 32;
            areg[it] = *(const int4*)(xh + (size_t)(n0 + r) * CDIM + cs + sc * 8);
            breg[it] = *(const int4*)(ch + (size_t)(k0 + r) * CDIM + cs + sc * 8);
        }
        __syncthreads();
        #pragma unroll
        for (int it = 0; it < 4; ++it) {
            int r = sr + it * 32;
            *(int4*)(sA + r * LDA + sc * 8) = areg[it];
            *(int4*)(sB + r * LDA + sc * 8) = breg[it];
        }
        __syncthreads();

        #pragma unroll
        for (int kk = 0; kk < 2; ++kk) {
            f16x8 af[2];
            #pragma unroll
            for (int mi = 0; mi < 2; ++mi) {
                int m = w * 32 + mi * 16 + cc2;
                af[mi] = *(const f16x8*)(sA + m * LDA + kk * 32 + qq * 8);
            }
            #pragma unroll
            for (int ni = 0; ni < 8; ++ni) {
                int nn = ni * 16 + cc2;
                f16x8 bf = *(const f16x8*)(sB + nn * LDA + kk * 32 + qq * 8);
                acc[0][ni] = __builtin_amdgcn_mfma_f32_16x16x32_f16(af[0], bf, acc[0][ni], 0, 0, 0);
                acc[1][ni] = __builtin_amdgcn_mfma_f32_16x16x32_f16(af[1], bf, acc[1][ni], 0, 0, 0);
            }
        }
    }

    // Epilogue: branch-free top-2 per row over 128 codes.
    // C/D layout: col = lane&15, row = (lane>>4)*4 + reg.
    #pragma unroll
    for (int mi = 0; mi < 2; ++mi) {
        #pragma unroll
        for (int r = 0; r < 4; ++r) {
            u64 c[8];
            #pragma unroll
            for (int ni = 0; ni < 8; ++ni)
                c[ni] = key_make(acc[mi][ni][r], k0 + ni * 16 + cc2);
            u64 k1 = c[0] > c[1] ? c[0] : c[1], k2 = c[0] > c[1] ? c[1] : c[0];
            u64 m1 = c[2] > c[3] ? c[2] : c[3], m2 = c[2] > c[3] ? c[3] : c[2];
            u64 p1 = c[4] > c[5] ? c[4] : c[5], p2 = c[4] > c[5] ? c[5] : c[4];
            u64 q1 = c[6] > c[7] ? c[6] : c[7], q2 = c[6] > c[7] ? c[7] : c[6];
            merge2(k1, k2, m1, m2);
            merge2(p1, p2, q1, q2);
            merge2(k1, k2, p1, p2);
            #pragma unroll
            for (int msk = 1; msk <= 8; msk <<= 1) {
                u64 o1 = (u64)__shfl_xor((long long)k1, msk);
                u64 o2 = (u64)__shfl_xor((long long)k2, msk);
                merge2(k1, k2, o1, o2);
            }
            if (cc2 == 0) {
                int row = w * 32 + mi * 16 + qq * 4 + r;
                ulonglong2 e; e.x = k1; e.y = k2;
                ptop[(size_t)kb * NROWS + n0 + row] = e;
            }
        }
    }
}

// =============== Kernel 3: merge 64 k-blocks -> global top-4 candidates =======
__global__ __launch_bounds__(256) void reduce_kernel(const ulonglong2* __restrict__ ptop,
                                                     int4* __restrict__ cand) {
    int n = blockIdx.x * 256 + threadIdx.x;   // 128 blocks
    u64 k[4] = {0ull, 0ull, 0ull, 0ull};
    for (int kb = 0; kb < NKB; ++kb) {
        ulonglong2 e = ptop[(size_t)kb * NROWS + n];
        ins4(e.x, k);
        ins4(e.y, k);
    }
    cand[n] = make_int4(key_idx(k[0]), key_idx(k[1]), key_idx(k[2]), key_idx(k[3]));
}

// =============== Kernel 4: exact fp32 rescore of 4 candidates + q write + loss =
__global__ __launch_bounds__(256) void rescore_kernel(const float* __restrict__ x,
                                                      const float* __restrict__ cb,
                                                      const int4* __restrict__ cand,
                                                      float* __restrict__ out,
                                                      float* __restrict__ loss_sum) {
    int blk = blockIdx.x;                 // 512 blocks, 64 rows each
    int b = blk >> 6;
    int p0 = (blk & 63) << 6;
    int t = threadIdx.x, w = t >> 6, lane = t & 63;
    size_t rowbase = (size_t)b * HWP + p0;
    int4 cd = cand[rowbase + lane];
    const float* xb = x + (size_t)b * CDIM * HWP + p0 + lane;
    const float* c0 = cb + (size_t)cd.x * CDIM;
    const float* c1 = cb + (size_t)cd.y * CDIM;
    const float* c2 = cb + (size_t)cd.z * CDIM;
    const float* c3 = cb + (size_t)cd.w * CDIM;
    float n2 = 0.f, d0 = 0.f, d1 = 0.f, d2 = 0.f, d3 = 0.f;
    for (int c = w * 64; c < w * 64 + 64; ++c) {
        float xv = xb[(size_t)c * HWP];
        n2 = fmaf(xv, xv, n2);
        d0 = fmaf(xv, c0[c], d0);
        d1 = fmaf(xv, c1[c], d1);
        d2 = fmaf(xv, c2[c], d2);
        d3 = fmaf(xv, c3[c], d3);
    }
    __shared__ float s_n2[4][64], s_d[4][4][64];
    __shared__ int   s_win[64];
    __shared__ float s_loss[64];
    s_n2[w][lane] = n2;
    s_d[0][w][lane] = d0; s_d[1][w][lane] = d1;
    s_d[2][w][lane] = d2; s_d[3][w][lane] = d3;
    __syncthreads();
    if (t < 64) {
        float N2 = s_n2[0][t] + s_n2[1][t] + s_n2[2][t] + s_n2[3][t];
        int4 cdt = cand[rowbase + t];
        int ids[4] = {cdt.x, cdt.y, cdt.z, cdt.w};
        float bD = -3.4e38f; int bI = 0x7fffffff;
        #pragma unroll
        for (int j = 0; j < 4; ++j) {
            float D = s_d[j][0][t] + s_d[j][1][t] + s_d[j][2][t] + s_d[j][3][t];
            if (D > bD || (D == bD && ids[j] < bI)) { bD = D; bI = ids[j]; }
        }
        s_win[t]  = bI;
        s_loss[t] = bD / fmaxf(sqrtf(N2), 1e-12f);
    }
    __syncthreads();
    if (w == 0) {
        float v = s_loss[lane];
        #pragma unroll
        for (int off = 32; off; off >>= 1) v += __shfl_down(v, off);
        if (lane == 0) atomicAdd(loss_sum, v);
    }
    int win = s_win[lane];
    const float* cw = cb + (size_t)win * CDIM;
    float* ob = out + (size_t)b * CDIM * HWP + p0 + lane;
    for (int c = w * 64; c < w * 64 + 64; ++c)
        ob[(size_t)c * HWP] = cw[c];
}

// =============== Kernel 5: finalize losses ====================================
__global__ void finalize_kernel(const float* __restrict__ loss_sum,
                                float* __restrict__ out) {
    if (threadIdx.x == 0) {
        float mean = loss_sum[0] / 32768.0f;
        out[8388608] = 0.25f * (1.0f - mean);
        out[8388609] = 1.0f  * (1.0f - mean);
    }
}

extern "C" void kernel_launch(void* const* d_in, const int* in_sizes, int n_in,
                              void* d_out, int out_size, void* d_ws, size_t ws_size,
                              hipStream_t stream) {
    const float* x  = (const float*)d_in[0];   // [8,256,64,64]
    const float* cb = (const float*)d_in[1];   // [8192,256]
    float* out = (float*)d_out;

    char* ws = (char*)d_ws;
    _Float16*   xh   = (_Float16*)  (ws);                 // 16,777,216 B
    _Float16*   ch   = (_Float16*)  (ws + 16777216);      //  4,194,304 B
    ulonglong2* ptop = (ulonglong2*)(ws + 20971520);      // 33,554,432 B
    int4*       cand = (int4*)      (ws + 54525952);      //    524,288 B
    float*      loss = (float*)     (ws + 55050240);      //          4 B

    hipMemsetAsync(loss, 0, 4, stream);
    split_x_kernel <<<dim3(64, 4, 8), 256, 0, stream>>>(x, xh);
    split_cb_kernel<<<2048,           256, 0, stream>>>(cb, ch);
    gemm_kernel    <<<16384,          256, 0, stream>>>(xh, ch, ptop);
    reduce_kernel  <<<128,            256, 0, stream>>>(ptop, cand);
    rescore_kernel <<<512,            256, 0, stream>>>(x, cb, cand, out, loss);
    finalize_kernel<<<1,              64,  0, stream>>>(loss, out);
}